// Round 1
// baseline (653.030 us; speedup 1.0000x reference)
//
#include <hip/hip_runtime.h>

// ---------------------------------------------------------------------------
// GCN pipeline: 3x (GEMM -> edge scatter-aggregate -> finalize), max-pool, MLP
// N=50000 nodes, E=800000 edges, F=H=64, G=512 graphs, C=10 classes
// ---------------------------------------------------------------------------

// Detect whether mask buffer is 1-byte bools or int32 0/1.
// If bytes: some aligned 4-byte word will have value > 1 (80% density).
__global__ void k_detect(const unsigned int* __restrict__ m, int n_ints,
                         int* __restrict__ flag) {
  int i = blockIdx.x * blockDim.x + threadIdx.x;
  for (; i < n_ints; i += blockDim.x * gridDim.x) {
    if (m[i] > 1u) *flag = 1;  // racy same-value store: fine
  }
}

__global__ void k_maskf(const void* __restrict__ mraw, const int* __restrict__ flag,
                        float* __restrict__ maskf, int N) {
  int i = blockIdx.x * blockDim.x + threadIdx.x;
  if (i >= N) return;
  float v;
  if (*flag) v = (float)((const unsigned char*)mraw)[i];
  else       v = (float)((const int*)mraw)[i];
  maskf[i] = v;
}

// deg[d] += 1 for each edge with both endpoints kept
__global__ void k_edge_deg(const int* __restrict__ src, const int* __restrict__ dst,
                           const float* __restrict__ maskf, float* __restrict__ deg,
                           int E) {
  int e = blockIdx.x * blockDim.x + threadIdx.x;
  if (e >= E) return;
  int s = src[e], d = dst[e];
  if (maskf[s] != 0.f && maskf[d] != 0.f) atomicAdd(&deg[d], 1.0f);
}

// dinv = deg+mask > 0 ? 1/sqrt(deg+mask) : 0   (deg+mask>0 iff node kept)
__global__ void k_dinv(const float* __restrict__ deg, const float* __restrict__ maskf,
                       float* __restrict__ dinv, int N) {
  int i = blockIdx.x * blockDim.x + threadIdx.x;
  if (i >= N) return;
  float d = deg[i] + maskf[i];
  dinv[i] = (d > 0.f) ? (1.0f / sqrtf(d)) : 0.f;
}

// norm_e = dinv[src]*dinv[dst]  (zero automatically when either dropped)
__global__ void k_edge_norm(const int* __restrict__ src, const int* __restrict__ dst,
                            const float* __restrict__ dinv, float* __restrict__ norm_e,
                            int E) {
  int e = blockIdx.x * blockDim.x + threadIdx.x;
  if (e >= E) return;
  norm_e[e] = dinv[src[e]] * dinv[dst[e]];
}

// T[r][f] = sum_k A[r][k]*(rowscale?rowscale[r]:1)*W[k][f]
// One wave per row; lane f holds W column f in 64 VGPRs; A row broadcast by shfl.
__global__ __launch_bounds__(256) void k_gemm64(const float* __restrict__ A,
                                                const float* __restrict__ rowscale,
                                                const float* __restrict__ W,
                                                float* __restrict__ T, int nrows) {
  const int lane = threadIdx.x & 63;
  const int wid = threadIdx.x >> 6;
  float wcol[64];
#pragma unroll
  for (int k = 0; k < 64; ++k) wcol[k] = W[k * 64 + lane];
  for (int r = blockIdx.x * 4 + wid; r < nrows; r += gridDim.x * 4) {
    float av = A[(long)r * 64 + lane];
    if (rowscale) av *= rowscale[r];
    float acc = 0.f;
#pragma unroll
    for (int k = 0; k < 64; ++k) acc = fmaf(__shfl(av, k), wcol[k], acc);
    T[(long)r * 64 + lane] = acc;
  }
}

// One wave per edge: AGG[dst][f] += T[src][f] * norm_e[e]
__global__ __launch_bounds__(256) void k_scatter(const int* __restrict__ src,
                                                 const int* __restrict__ dst,
                                                 const float* __restrict__ norm_e,
                                                 const float* __restrict__ T,
                                                 float* __restrict__ AGG, int E) {
  const int lane = threadIdx.x & 63;
  const int e = blockIdx.x * 4 + (threadIdx.x >> 6);
  if (e >= E) return;
  float w = norm_e[e];
  if (w == 0.f) return;  // wave-uniform skip (36% of edges)
  int s = src[e], d = dst[e];
  float v = T[(long)s * 64 + lane] * w;
  atomicAdd(&AGG[(long)d * 64 + lane], v);
}

// Hout = relu(AGG + T*dinv^2 + b)
__global__ void k_finalize(const float* __restrict__ AGG, const float* __restrict__ T,
                           const float* __restrict__ dinv, const float* __restrict__ b,
                           float* __restrict__ Hout, int N) {
  long idx = (long)blockIdx.x * blockDim.x + threadIdx.x;
  if (idx >= (long)N * 64) return;
  int i = (int)(idx >> 6), f = (int)(idx & 63);
  float di = dinv[i];
  Hout[idx] = fmaxf(AGG[idx] + T[idx] * di * di + b[f], 0.f);
}

// g[batch[i]][f] = max over kept i of H[i][f]; H>=0 post-relu so int-bits
// atomicMax with g init to 0 reproduces reference (-inf -> 0 for empty).
__global__ __launch_bounds__(256) void k_pool(const float* __restrict__ H,
                                              const float* __restrict__ maskf,
                                              const int* __restrict__ batch,
                                              float* __restrict__ g, int N) {
  const int lane = threadIdx.x & 63;
  const int i = blockIdx.x * 4 + (threadIdx.x >> 6);
  if (i >= N) return;
  if (maskf[i] == 0.f) return;
  int b = batch[i];
  float v = H[(long)i * 64 + lane];
  atomicMax((int*)&g[b * 64 + lane], __float_as_int(v));
}

// g2 = relu(g @ fw1 + fb1)   [G,64]x[64,64]
__global__ void k_head1(const float* __restrict__ g, const float* __restrict__ fw1,
                        const float* __restrict__ fb1, float* __restrict__ g2) {
  int r = blockIdx.x, f = threadIdx.x;
  float acc = fb1[f];
  for (int k = 0; k < 64; ++k) acc = fmaf(g[r * 64 + k], fw1[k * 64 + f], acc);
  g2[r * 64 + f] = fmaxf(acc, 0.f);
}

// out = g2 @ fw2 + fb2   [G,64]x[64,C]
__global__ void k_head2(const float* __restrict__ g2, const float* __restrict__ fw2,
                        const float* __restrict__ fb2, float* __restrict__ out, int C) {
  int r = blockIdx.x, f = threadIdx.x;
  if (f >= C) return;
  float acc = fb2[f];
  for (int k = 0; k < 64; ++k) acc = fmaf(g2[r * 64 + k], fw2[k * C + f], acc);
  out[r * C + f] = acc;
}

extern "C" void kernel_launch(void* const* d_in, const int* in_sizes, int n_in,
                              void* d_out, int out_size, void* d_ws, size_t ws_size,
                              hipStream_t stream) {
  const float* x    = (const float*)d_in[0];
  const int*   ei   = (const int*)d_in[1];
  const int*   batch= (const int*)d_in[2];
  const void*  mraw = d_in[3];
  const float* W1   = (const float*)d_in[4];
  const float* b1   = (const float*)d_in[5];
  const float* W2   = (const float*)d_in[6];
  const float* b2   = (const float*)d_in[7];
  const float* W3   = (const float*)d_in[8];
  const float* b3   = (const float*)d_in[9];
  const float* fw1  = (const float*)d_in[10];
  const float* fb1  = (const float*)d_in[11];
  const float* fw2  = (const float*)d_in[12];
  const float* fb2  = (const float*)d_in[13];
  float* out = (float*)d_out;

  const int N = in_sizes[0] / 64;
  const int E = in_sizes[1] / 2;
  const int C = in_sizes[13];
  const int G = out_size / C;
  const int* src = ei;
  const int* dst = ei + E;

  char* ws = (char*)d_ws;
  size_t off = 0;
  auto alloc = [&](size_t bytes) -> void* {
    void* p = ws + off;
    off += (bytes + 255) & ~(size_t)255;
    return p;
  };
  int*   flag   = (int*)alloc(sizeof(int));
  float* maskf  = (float*)alloc((size_t)N * 4);
  float* deg    = (float*)alloc((size_t)N * 4);
  float* dinv   = (float*)alloc((size_t)N * 4);
  float* norm_e = (float*)alloc((size_t)E * 4);
  float* T      = (float*)alloc((size_t)N * 64 * 4);
  float* AGG    = (float*)alloc((size_t)N * 64 * 4);
  float* HA     = (float*)alloc((size_t)N * 64 * 4);
  float* HB     = (float*)alloc((size_t)N * 64 * 4);
  float* gbuf   = (float*)alloc((size_t)G * 64 * 4);
  float* g2buf  = (float*)alloc((size_t)G * 64 * 4);
  (void)ws_size;

  hipMemsetAsync(flag, 0, sizeof(int), stream);
  hipMemsetAsync(deg, 0, (size_t)N * 4, stream);
  hipMemsetAsync(gbuf, 0, (size_t)G * 64 * 4, stream);

  int n_ints = N / 4;
  k_detect<<<32, 256, 0, stream>>>((const unsigned int*)mraw, n_ints, flag);
  k_maskf<<<(N + 255) / 256, 256, 0, stream>>>(mraw, flag, maskf, N);
  k_edge_deg<<<(E + 255) / 256, 256, 0, stream>>>(src, dst, maskf, deg, E);
  k_dinv<<<(N + 255) / 256, 256, 0, stream>>>(deg, maskf, dinv, N);
  k_edge_norm<<<(E + 255) / 256, 256, 0, stream>>>(src, dst, dinv, norm_e, E);

  const int gemm_blocks = 2048;
  const int scat_blocks = (E + 3) / 4;
  const int fin_blocks = (int)(((long)N * 64 + 255) / 256);

  // layer 1
  k_gemm64<<<gemm_blocks, 256, 0, stream>>>(x, maskf, W1, T, N);
  hipMemsetAsync(AGG, 0, (size_t)N * 64 * 4, stream);
  k_scatter<<<scat_blocks, 256, 0, stream>>>(src, dst, norm_e, T, AGG, E);
  k_finalize<<<fin_blocks, 256, 0, stream>>>(AGG, T, dinv, b1, HA, N);
  // layer 2
  k_gemm64<<<gemm_blocks, 256, 0, stream>>>(HA, nullptr, W2, T, N);
  hipMemsetAsync(AGG, 0, (size_t)N * 64 * 4, stream);
  k_scatter<<<scat_blocks, 256, 0, stream>>>(src, dst, norm_e, T, AGG, E);
  k_finalize<<<fin_blocks, 256, 0, stream>>>(AGG, T, dinv, b2, HB, N);
  // layer 3
  k_gemm64<<<gemm_blocks, 256, 0, stream>>>(HB, nullptr, W3, T, N);
  hipMemsetAsync(AGG, 0, (size_t)N * 64 * 4, stream);
  k_scatter<<<scat_blocks, 256, 0, stream>>>(src, dst, norm_e, T, AGG, E);
  k_finalize<<<fin_blocks, 256, 0, stream>>>(AGG, T, dinv, b3, HA, N);

  k_pool<<<(N + 3) / 4, 256, 0, stream>>>(HA, maskf, batch, gbuf, N);
  k_head1<<<G, 64, 0, stream>>>(gbuf, fw1, fb1, g2buf);
  k_head2<<<G, 64, 0, stream>>>(g2buf, fw2, fb2, out, C);
}

// Round 2
// 355.293 us; speedup vs baseline: 1.8380x; 1.8380x over previous
//
#include <hip/hip_runtime.h>

// ---------------------------------------------------------------------------
// GCN pipeline v2: CSR-based atomic-free aggregation fused with 64x64 GEMM.
// N=50000 nodes, E=800000 edges, H=F=64, G=512 graphs, C=10 classes
// ---------------------------------------------------------------------------

// Detect whether mask buffer is 1-byte bools or int32 0/1.
__global__ void k_detect(const unsigned int* __restrict__ m, int n_ints,
                         int* __restrict__ flag) {
  int i = blockIdx.x * blockDim.x + threadIdx.x;
  for (; i < n_ints; i += blockDim.x * gridDim.x) {
    if (m[i] > 1u) *flag = 1;
  }
}

__global__ void k_maskf(const void* __restrict__ mraw, const int* __restrict__ flag,
                        float* __restrict__ maskf, int N) {
  int i = blockIdx.x * blockDim.x + threadIdx.x;
  if (i >= N) return;
  float v;
  if (*flag) v = (float)((const unsigned char*)mraw)[i];
  else       v = (float)((const int*)mraw)[i];
  maskf[i] = v;
}

// cnt[d] += 1 for each edge with both endpoints kept
__global__ void k_cnt(const int* __restrict__ src, const int* __restrict__ dst,
                      const float* __restrict__ maskf, int* __restrict__ cnt, int E) {
  int e = blockIdx.x * blockDim.x + threadIdx.x;
  if (e >= E) return;
  int s = src[e], d = dst[e];
  if (maskf[s] != 0.f && maskf[d] != 0.f) atomicAdd(&cnt[d], 1);
}

// dinv = (cnt+mask) > 0 ? rsqrt(cnt+mask) : 0
__global__ void k_dinv(const int* __restrict__ cnt, const float* __restrict__ maskf,
                       float* __restrict__ dinv, int N) {
  int i = blockIdx.x * blockDim.x + threadIdx.x;
  if (i >= N) return;
  float d = (float)cnt[i] + maskf[i];
  dinv[i] = (d > 0.f) ? rsqrtf(d) : 0.f;
}

// --- 3-kernel exclusive scan of cnt[N] -> off[N] (nb <= 256 block sums) ---
__global__ void k_scan1(const int* __restrict__ cnt, int* __restrict__ off,
                        int* __restrict__ bsum, int N) {
  __shared__ int s[256];
  int i = blockIdx.x * 256 + threadIdx.x;
  int v = (i < N) ? cnt[i] : 0;
  s[threadIdx.x] = v;
  __syncthreads();
#pragma unroll
  for (int d = 1; d < 256; d <<= 1) {
    int t = (threadIdx.x >= d) ? s[threadIdx.x - d] : 0;
    __syncthreads();
    s[threadIdx.x] += t;
    __syncthreads();
  }
  if (i < N) off[i] = s[threadIdx.x] - v;  // block-local exclusive
  if (threadIdx.x == 255) bsum[blockIdx.x] = s[255];
}

__global__ void k_scan2(int* __restrict__ bsum, int nb) {
  __shared__ int s[256];
  int v = (threadIdx.x < nb) ? bsum[threadIdx.x] : 0;
  s[threadIdx.x] = v;
  __syncthreads();
#pragma unroll
  for (int d = 1; d < 256; d <<= 1) {
    int t = (threadIdx.x >= d) ? s[threadIdx.x - d] : 0;
    __syncthreads();
    s[threadIdx.x] += t;
    __syncthreads();
  }
  if (threadIdx.x < nb) bsum[threadIdx.x] = s[threadIdx.x] - v;  // exclusive
}

__global__ void k_scan3(int* __restrict__ off, const int* __restrict__ bsum,
                        int* __restrict__ cursor, int N) {
  int i = blockIdx.x * 256 + threadIdx.x;
  if (i >= N) return;
  int o = off[i] + bsum[blockIdx.x];
  off[i] = o;
  cursor[i] = o;
}

// Fill CSR: packed (src, w_bits) per kept edge, grouped by dst.
__global__ void k_fill(const int* __restrict__ src, const int* __restrict__ dst,
                       const float* __restrict__ dinv, int* __restrict__ cursor,
                       int2* __restrict__ csr, int E) {
  int e = blockIdx.x * blockDim.x + threadIdx.x;
  if (e >= E) return;
  int s = src[e], d = dst[e];
  float w = dinv[s] * dinv[d];
  if (w > 0.f) {
    int p = atomicAdd(&cursor[d], 1);
    csr[p] = make_int2(s, __float_as_int(w));
  }
}

// Fused GCN layer: one wave per dst node.
// agg[lane] = Hin[d][lane]*dinv[d]^2 + sum_e Hin[src_e][lane]*w_e
// Hout[d][lane] = relu( sum_k agg[k]*W[k][lane] + b[lane] )
__global__ __launch_bounds__(256) void k_layer(const float* __restrict__ Hin,
                                               const float* __restrict__ dinv,
                                               const int* __restrict__ off,
                                               const int* __restrict__ cnt,
                                               const int2* __restrict__ csr,
                                               const float* __restrict__ W,
                                               const float* __restrict__ b,
                                               float* __restrict__ Hout, int N) {
  const int lane = threadIdx.x & 63;
  const int wid = threadIdx.x >> 6;
  float wcol[64];
#pragma unroll
  for (int k = 0; k < 64; ++k) wcol[k] = W[k * 64 + lane];
  const int d = blockIdx.x * 4 + wid;
  if (d >= N) return;
  const float di = dinv[d];
  const int base = off[d];
  const int n = cnt[d];
  float agg = Hin[(long)d * 64 + lane] * di * di;
  int i = 0;
  for (; i + 2 <= n; i += 2) {
    int2 e0 = csr[base + i];
    int2 e1 = csr[base + i + 1];
    float v0 = Hin[(long)e0.x * 64 + lane];
    float v1 = Hin[(long)e1.x * 64 + lane];
    agg = fmaf(v0, __int_as_float(e0.y), agg);
    agg = fmaf(v1, __int_as_float(e1.y), agg);
  }
  if (i < n) {
    int2 e0 = csr[base + i];
    agg = fmaf(Hin[(long)e0.x * 64 + lane], __int_as_float(e0.y), agg);
  }
  float z = b[lane];
#pragma unroll
  for (int k = 0; k < 64; ++k) z = fmaf(__shfl(agg, k), wcol[k], z);
  Hout[(long)d * 64 + lane] = fmaxf(z, 0.f);
}

// Per-graph node index bounds (batch is sorted).
__global__ void k_bounds(const int* __restrict__ batch, int* __restrict__ gs,
                         int* __restrict__ ge, int N) {
  int i = blockIdx.x * blockDim.x + threadIdx.x;
  if (i >= N) return;
  int b = batch[i];
  atomicMin(&gs[b], i);
  atomicMax(&ge[b], i);
}

// Per-graph max-pool over kept nodes (H >= 0 post-relu; empty graph -> 0).
__global__ __launch_bounds__(256) void k_pool(const float* __restrict__ H,
                                              const float* __restrict__ maskf,
                                              const int* __restrict__ gs,
                                              const int* __restrict__ ge,
                                              float* __restrict__ g, int N) {
  __shared__ float sP[4][64];
  const int grp = blockIdx.x;
  const int lane = threadIdx.x & 63, wid = threadIdx.x >> 6;
  const int s = gs[grp], e = ge[grp];
  float v = 0.f;
  for (int i = s + wid; i <= e && i < N; i += 4)
    if (maskf[i] != 0.f) v = fmaxf(v, H[(long)i * 64 + lane]);
  sP[wid][lane] = v;
  __syncthreads();
  if (wid == 0) {
    v = fmaxf(fmaxf(sP[0][lane], sP[1][lane]), fmaxf(sP[2][lane], sP[3][lane]));
    g[grp * 64 + lane] = v;
  }
}

// g2 = relu(g @ fw1 + fb1)   [G,64]x[64,64]
__global__ void k_head1(const float* __restrict__ g, const float* __restrict__ fw1,
                        const float* __restrict__ fb1, float* __restrict__ g2) {
  int r = blockIdx.x, f = threadIdx.x;
  float acc = fb1[f];
  for (int k = 0; k < 64; ++k) acc = fmaf(g[r * 64 + k], fw1[k * 64 + f], acc);
  g2[r * 64 + f] = fmaxf(acc, 0.f);
}

// out = g2 @ fw2 + fb2   [G,64]x[64,C]
__global__ void k_head2(const float* __restrict__ g2, const float* __restrict__ fw2,
                        const float* __restrict__ fb2, float* __restrict__ out, int C) {
  int r = blockIdx.x, f = threadIdx.x;
  if (f >= C) return;
  float acc = fb2[f];
  for (int k = 0; k < 64; ++k) acc = fmaf(g2[r * 64 + k], fw2[k * C + f], acc);
  out[r * C + f] = acc;
}

extern "C" void kernel_launch(void* const* d_in, const int* in_sizes, int n_in,
                              void* d_out, int out_size, void* d_ws, size_t ws_size,
                              hipStream_t stream) {
  const float* x    = (const float*)d_in[0];
  const int*   ei   = (const int*)d_in[1];
  const int*   batch= (const int*)d_in[2];
  const void*  mraw = d_in[3];
  const float* W1   = (const float*)d_in[4];
  const float* b1   = (const float*)d_in[5];
  const float* W2   = (const float*)d_in[6];
  const float* b2   = (const float*)d_in[7];
  const float* W3   = (const float*)d_in[8];
  const float* b3   = (const float*)d_in[9];
  const float* fw1  = (const float*)d_in[10];
  const float* fb1  = (const float*)d_in[11];
  const float* fw2  = (const float*)d_in[12];
  const float* fb2  = (const float*)d_in[13];
  float* out = (float*)d_out;

  const int N = in_sizes[0] / 64;
  const int E = in_sizes[1] / 2;
  const int C = in_sizes[13];
  const int G = out_size / C;
  const int* src = ei;
  const int* dst = ei + E;

  char* ws = (char*)d_ws;
  size_t off_b = 0;
  auto alloc = [&](size_t bytes) -> void* {
    void* p = ws + off_b;
    off_b += (bytes + 255) & ~(size_t)255;
    return p;
  };
  int*   flag   = (int*)alloc(sizeof(int));
  float* maskf  = (float*)alloc((size_t)N * 4);
  int*   cnt    = (int*)alloc((size_t)N * 4);
  float* dinv   = (float*)alloc((size_t)N * 4);
  int*   off    = (int*)alloc((size_t)N * 4);
  int*   cursor = (int*)alloc((size_t)N * 4);
  int*   bsum   = (int*)alloc(256 * 4);
  int*   gs     = (int*)alloc((size_t)G * 4);
  int*   ge     = (int*)alloc((size_t)G * 4);
  int2*  csr    = (int2*)alloc((size_t)E * 8);
  float* HA     = (float*)alloc((size_t)N * 64 * 4);
  float* HB     = (float*)alloc((size_t)N * 64 * 4);
  float* gbuf   = (float*)alloc((size_t)G * 64 * 4);
  float* g2buf  = (float*)alloc((size_t)G * 64 * 4);
  (void)ws_size;

  hipMemsetAsync(flag, 0, sizeof(int), stream);
  hipMemsetAsync(cnt, 0, (size_t)N * 4, stream);
  hipMemsetAsync(gs, 0x7f, (size_t)G * 4, stream);
  hipMemsetAsync(ge, 0, (size_t)G * 4, stream);

  const int nb = (N + 255) / 256;
  k_detect<<<32, 256, 0, stream>>>((const unsigned int*)mraw, N / 4, flag);
  k_maskf<<<nb, 256, 0, stream>>>(mraw, flag, maskf, N);
  k_cnt<<<(E + 255) / 256, 256, 0, stream>>>(src, dst, maskf, cnt, E);
  k_dinv<<<nb, 256, 0, stream>>>(cnt, maskf, dinv, N);
  k_scan1<<<nb, 256, 0, stream>>>(cnt, off, bsum, N);
  k_scan2<<<1, 256, 0, stream>>>(bsum, nb);
  k_scan3<<<nb, 256, 0, stream>>>(off, bsum, cursor, N);
  k_fill<<<(E + 255) / 256, 256, 0, stream>>>(src, dst, dinv, cursor, csr, E);

  const int lay_blocks = (N + 3) / 4;
  k_layer<<<lay_blocks, 256, 0, stream>>>(x,  dinv, off, cnt, csr, W1, b1, HA, N);
  k_layer<<<lay_blocks, 256, 0, stream>>>(HA, dinv, off, cnt, csr, W2, b2, HB, N);
  k_layer<<<lay_blocks, 256, 0, stream>>>(HB, dinv, off, cnt, csr, W3, b3, HA, N);

  k_bounds<<<nb, 256, 0, stream>>>(batch, gs, ge, N);
  k_pool<<<G, 256, 0, stream>>>(HA, maskf, gs, ge, gbuf, N);
  k_head1<<<G, 64, 0, stream>>>(gbuf, fw1, fb1, g2buf);
  k_head2<<<G, 64, 0, stream>>>(g2buf, fw2, fb2, out, C);
}

// Round 3
// 323.731 us; speedup vs baseline: 2.0172x; 1.0975x over previous
//
#include <hip/hip_runtime.h>

// ---------------------------------------------------------------------------
// GCN pipeline v3: CSR gather (4-edge/iter float4 groups) + separate dense GEMM
// N=50000 nodes, E=800000 edges, H=F=64, G=512 graphs, C=10 classes
// ---------------------------------------------------------------------------

// Detect whether mask buffer is 1-byte bools or int32 0/1.
__global__ void k_detect(const unsigned int* __restrict__ m, int n_ints,
                         int* __restrict__ flag) {
  int i = blockIdx.x * blockDim.x + threadIdx.x;
  for (; i < n_ints; i += blockDim.x * gridDim.x) {
    if (m[i] > 1u) *flag = 1;
  }
}

// maskf + zero cnt + init gs/ge
__global__ void k_maskf(const void* __restrict__ mraw, const int* __restrict__ flag,
                        float* __restrict__ maskf, int* __restrict__ cnt,
                        int* __restrict__ gs, int* __restrict__ ge, int N, int G) {
  int i = blockIdx.x * blockDim.x + threadIdx.x;
  if (i < G) { gs[i] = 0x7fffffff; ge[i] = -1; }
  if (i >= N) return;
  float v;
  if (*flag) v = (float)((const unsigned char*)mraw)[i];
  else       v = (float)((const int*)mraw)[i];
  maskf[i] = v;
  cnt[i] = 0;
}

// cnt[d] += 1 for each edge with both endpoints kept
__global__ void k_cnt(const int* __restrict__ src, const int* __restrict__ dst,
                      const float* __restrict__ maskf, int* __restrict__ cnt, int E) {
  int e = blockIdx.x * blockDim.x + threadIdx.x;
  if (e >= E) return;
  int s = src[e], d = dst[e];
  if (maskf[s] != 0.f && maskf[d] != 0.f) atomicAdd(&cnt[d], 1);
}

// scan1 + dinv fused
__global__ void k_scan1(const int* __restrict__ cnt, const float* __restrict__ maskf,
                        float* __restrict__ dinv, int* __restrict__ off,
                        int* __restrict__ bsum, int N) {
  __shared__ int s[256];
  int i = blockIdx.x * 256 + threadIdx.x;
  int v = (i < N) ? cnt[i] : 0;
  if (i < N) {
    float d = (float)v + maskf[i];
    dinv[i] = (d > 0.f) ? rsqrtf(d) : 0.f;
  }
  s[threadIdx.x] = v;
  __syncthreads();
#pragma unroll
  for (int d = 1; d < 256; d <<= 1) {
    int t = (threadIdx.x >= d) ? s[threadIdx.x - d] : 0;
    __syncthreads();
    s[threadIdx.x] += t;
    __syncthreads();
  }
  if (i < N) off[i] = s[threadIdx.x] - v;
  if (threadIdx.x == 255) bsum[blockIdx.x] = s[255];
}

__global__ void k_scan2(int* __restrict__ bsum, int nb) {
  __shared__ int s[256];
  int v = (threadIdx.x < nb) ? bsum[threadIdx.x] : 0;
  s[threadIdx.x] = v;
  __syncthreads();
#pragma unroll
  for (int d = 1; d < 256; d <<= 1) {
    int t = (threadIdx.x >= d) ? s[threadIdx.x - d] : 0;
    __syncthreads();
    s[threadIdx.x] += t;
    __syncthreads();
  }
  if (threadIdx.x < nb) bsum[threadIdx.x] = s[threadIdx.x] - v;
}

// scan3 + cursor + per-graph bounds fused
__global__ void k_scan3(int* __restrict__ off, const int* __restrict__ bsum,
                        int* __restrict__ cursor, const int* __restrict__ batch,
                        int* __restrict__ gs, int* __restrict__ ge, int N) {
  int i = blockIdx.x * 256 + threadIdx.x;
  if (i >= N) return;
  int o = off[i] + bsum[blockIdx.x];
  off[i] = o;
  cursor[i] = o;
  int b = batch[i];
  atomicMin(&gs[b], i);
  atomicMax(&ge[b], i);
}

// Fill CSR: packed (src, w_bits) per kept edge, grouped by dst.
__global__ void k_fill(const int* __restrict__ src, const int* __restrict__ dst,
                       const float* __restrict__ dinv, int* __restrict__ cursor,
                       int2* __restrict__ csr, int E) {
  int e = blockIdx.x * blockDim.x + threadIdx.x;
  if (e >= E) return;
  int s = src[e], d = dst[e];
  float w = dinv[s] * dinv[d];
  if (w > 0.f) {
    int p = atomicAdd(&cursor[d], 1);
    csr[p] = make_int2(s, __float_as_int(w));
  }
}

// P[d][:] = dinv[d]^2 * Hin[d][:] + sum_e w_e * Hin[src_e][:]
// One wave per dst. CSR entries preloaded into lane regs; 4 edges / iteration
// via 16-lane float4 groups; butterfly reduce across groups at the end.
__global__ __launch_bounds__(256) void k_agg(const float* __restrict__ Hin,
                                             const float* __restrict__ dinv,
                                             const int* __restrict__ off,
                                             const int* __restrict__ cnt,
                                             const int2* __restrict__ csr,
                                             float* __restrict__ P, int N) {
  const int lane = threadIdx.x & 63;
  const int wid = threadIdx.x >> 6;
  const int d = blockIdx.x * 4 + wid;
  if (d >= N) return;
  const int grp = lane >> 4;   // which edge of the quad
  const int q = lane & 15;     // column group: cols 4q..4q+3
  const int base = off[d];
  const int n = cnt[d];
  float4 acc = make_float4(0.f, 0.f, 0.f, 0.f);
  int done = 0;
  while (done < n) {
    const int chunk = min(n - done, 64);
    int2 ce = (lane < chunk) ? csr[base + done + lane] : make_int2(0, 0);
    const int rounds = (chunk + 3) & ~3;
#pragma unroll 2
    for (int i = 0; i < rounds; i += 4) {
      const int j = i + grp;
      const int s = __shfl(ce.x, j);
      const float w = __int_as_float(__shfl(ce.y, j));  // 0 for padded lanes
      const float4 v = *(const float4*)&Hin[(long)s * 64 + q * 4];
      acc.x = fmaf(v.x, w, acc.x);
      acc.y = fmaf(v.y, w, acc.y);
      acc.z = fmaf(v.z, w, acc.z);
      acc.w = fmaf(v.w, w, acc.w);
    }
    done += chunk;
  }
  // reduce the 4 edge-groups (lanes l, l+16, l+32, l+48 share columns)
#pragma unroll
  for (int m = 16; m <= 32; m <<= 1) {
    acc.x += __shfl_xor(acc.x, m);
    acc.y += __shfl_xor(acc.y, m);
    acc.z += __shfl_xor(acc.z, m);
    acc.w += __shfl_xor(acc.w, m);
  }
  if (grp == 0) {
    const float di = dinv[d];
    const float dii = di * di;
    const float4 v = *(const float4*)&Hin[(long)d * 64 + q * 4];
    float4 r;
    r.x = fmaf(v.x, dii, acc.x);
    r.y = fmaf(v.y, dii, acc.y);
    r.z = fmaf(v.z, dii, acc.z);
    r.w = fmaf(v.w, dii, acc.w);
    *(float4*)&P[(long)d * 64 + q * 4] = r;
  }
}

// Hout = relu(A @ W + b); one wave per row, W column per lane.
__global__ __launch_bounds__(256) void k_gemm(const float* __restrict__ A,
                                              const float* __restrict__ W,
                                              const float* __restrict__ b,
                                              float* __restrict__ T, int nrows) {
  const int lane = threadIdx.x & 63;
  const int wid = threadIdx.x >> 6;
  float wcol[64];
#pragma unroll
  for (int k = 0; k < 64; ++k) wcol[k] = W[k * 64 + lane];
  const float bl = b[lane];
  for (int r = blockIdx.x * 4 + wid; r < nrows; r += gridDim.x * 4) {
    const float av = A[(long)r * 64 + lane];
    float acc = bl;
#pragma unroll
    for (int k = 0; k < 64; ++k) acc = fmaf(__shfl(av, k), wcol[k], acc);
    T[(long)r * 64 + lane] = fmaxf(acc, 0.f);
  }
}

// Fused: per-graph max-pool over kept nodes -> MLP head -> out[grp][:]
__global__ __launch_bounds__(256) void k_pool_head(
    const float* __restrict__ H, const float* __restrict__ maskf,
    const int* __restrict__ gs, const int* __restrict__ ge,
    const float* __restrict__ fw1, const float* __restrict__ fb1,
    const float* __restrict__ fw2, const float* __restrict__ fb2,
    float* __restrict__ out, int N, int C) {
  __shared__ float sP[4][64];
  __shared__ float sg[64];
  __shared__ float sg2[64];
  const int grp = blockIdx.x;
  const int lane = threadIdx.x & 63, wid = threadIdx.x >> 6;
  const int s = gs[grp], e = ge[grp];
  float v = 0.f;
  for (int i = s + wid; i <= e && i < N; i += 4)
    if (maskf[i] != 0.f) v = fmaxf(v, H[(long)i * 64 + lane]);
  sP[wid][lane] = v;
  __syncthreads();
  if (wid == 0)
    sg[lane] = fmaxf(fmaxf(sP[0][lane], sP[1][lane]), fmaxf(sP[2][lane], sP[3][lane]));
  __syncthreads();
  if (threadIdx.x < 64) {
    const int f = threadIdx.x;
    float acc = fb1[f];
#pragma unroll 8
    for (int k = 0; k < 64; ++k) acc = fmaf(sg[k], fw1[k * 64 + f], acc);
    sg2[f] = fmaxf(acc, 0.f);
  }
  __syncthreads();
  if (threadIdx.x < C) {
    const int c = threadIdx.x;
    float acc = fb2[c];
#pragma unroll 8
    for (int k = 0; k < 64; ++k) acc = fmaf(sg2[k], fw2[k * C + c], acc);
    out[grp * C + c] = acc;
  }
}

extern "C" void kernel_launch(void* const* d_in, const int* in_sizes, int n_in,
                              void* d_out, int out_size, void* d_ws, size_t ws_size,
                              hipStream_t stream) {
  const float* x    = (const float*)d_in[0];
  const int*   ei   = (const int*)d_in[1];
  const int*   batch= (const int*)d_in[2];
  const void*  mraw = d_in[3];
  const float* W1   = (const float*)d_in[4];
  const float* b1   = (const float*)d_in[5];
  const float* W2   = (const float*)d_in[6];
  const float* b2   = (const float*)d_in[7];
  const float* W3   = (const float*)d_in[8];
  const float* b3   = (const float*)d_in[9];
  const float* fw1  = (const float*)d_in[10];
  const float* fb1  = (const float*)d_in[11];
  const float* fw2  = (const float*)d_in[12];
  const float* fb2  = (const float*)d_in[13];
  float* out = (float*)d_out;

  const int N = in_sizes[0] / 64;
  const int E = in_sizes[1] / 2;
  const int C = in_sizes[13];
  const int* src = ei;
  const int* dst = ei + E;
  const int G = out_size / C;

  char* ws = (char*)d_ws;
  size_t off_b = 0;
  auto alloc = [&](size_t bytes) -> void* {
    void* p = ws + off_b;
    off_b += (bytes + 255) & ~(size_t)255;
    return p;
  };
  int*   flag   = (int*)alloc(sizeof(int));
  float* maskf  = (float*)alloc((size_t)N * 4);
  int*   cnt    = (int*)alloc((size_t)N * 4);
  float* dinv   = (float*)alloc((size_t)N * 4);
  int*   off    = (int*)alloc((size_t)N * 4);
  int*   cursor = (int*)alloc((size_t)N * 4);
  int*   bsum   = (int*)alloc(256 * 4);
  int*   gs     = (int*)alloc((size_t)G * 4);
  int*   ge     = (int*)alloc((size_t)G * 4);
  int2*  csr    = (int2*)alloc((size_t)E * 8);
  float* P      = (float*)alloc((size_t)N * 64 * 4);
  float* HA     = (float*)alloc((size_t)N * 64 * 4);
  float* HB     = (float*)alloc((size_t)N * 64 * 4);
  (void)ws_size;

  hipMemsetAsync(flag, 0, sizeof(int), stream);

  const int nb = (N + 255) / 256;
  k_detect<<<32, 256, 0, stream>>>((const unsigned int*)mraw, N / 4, flag);
  k_maskf<<<nb, 256, 0, stream>>>(mraw, flag, maskf, cnt, gs, ge, N, G);
  k_cnt<<<(E + 255) / 256, 256, 0, stream>>>(src, dst, maskf, cnt, E);
  k_scan1<<<nb, 256, 0, stream>>>(cnt, maskf, dinv, off, bsum, N);
  k_scan2<<<1, 256, 0, stream>>>(bsum, nb);
  k_scan3<<<nb, 256, 0, stream>>>(off, bsum, cursor, batch, gs, ge, N);
  k_fill<<<(E + 255) / 256, 256, 0, stream>>>(src, dst, dinv, cursor, csr, E);

  const int agg_blocks = (N + 3) / 4;
  const int gemm_blocks = 2048;
  // layer 1
  k_agg<<<agg_blocks, 256, 0, stream>>>(x, dinv, off, cnt, csr, P, N);
  k_gemm<<<gemm_blocks, 256, 0, stream>>>(P, W1, b1, HA, N);
  // layer 2
  k_agg<<<agg_blocks, 256, 0, stream>>>(HA, dinv, off, cnt, csr, P, N);
  k_gemm<<<gemm_blocks, 256, 0, stream>>>(P, W2, b2, HB, N);
  // layer 3
  k_agg<<<agg_blocks, 256, 0, stream>>>(HB, dinv, off, cnt, csr, P, N);
  k_gemm<<<gemm_blocks, 256, 0, stream>>>(P, W3, b3, HA, N);

  k_pool_head<<<G, 256, 0, stream>>>(HA, maskf, gs, ge, fw1, fb1, fw2, fb2, out, N, C);
}

// Round 4
// 277.512 us; speedup vs baseline: 2.3532x; 1.1665x over previous
//
#include <hip/hip_runtime.h>

// ---------------------------------------------------------------------------
// GCN pipeline v4: atomic-free graph bounds; 8-edge/iter CSR gather.
// N=50000 nodes, E=800000 edges, H=F=64, G=512 graphs, C=10 classes
// ---------------------------------------------------------------------------

// Detect whether mask buffer is 1-byte bools or int32 0/1.
__global__ void k_detect(const unsigned int* __restrict__ m, int n_ints,
                         int* __restrict__ flag) {
  int i = blockIdx.x * blockDim.x + threadIdx.x;
  for (; i < n_ints; i += blockDim.x * gridDim.x) {
    if (m[i] > 1u) *flag = 1;
  }
}

// maskf + zero cnt + init gs/ge
__global__ void k_maskf(const void* __restrict__ mraw, const int* __restrict__ flag,
                        float* __restrict__ maskf, int* __restrict__ cnt,
                        int* __restrict__ gs, int* __restrict__ ge, int N, int G) {
  int i = blockIdx.x * blockDim.x + threadIdx.x;
  if (i < G) { gs[i] = 0x7fffffff; ge[i] = -1; }
  if (i >= N) return;
  float v;
  if (*flag) v = (float)((const unsigned char*)mraw)[i];
  else       v = (float)((const int*)mraw)[i];
  maskf[i] = v;
  cnt[i] = 0;
}

// cnt[d] += 1 for each edge with both endpoints kept
__global__ void k_cnt(const int* __restrict__ src, const int* __restrict__ dst,
                      const float* __restrict__ maskf, int* __restrict__ cnt, int E) {
  int e = blockIdx.x * blockDim.x + threadIdx.x;
  if (e >= E) return;
  int s = src[e], d = dst[e];
  if (maskf[s] != 0.f && maskf[d] != 0.f) atomicAdd(&cnt[d], 1);
}

// scan1 + dinv fused
__global__ void k_scan1(const int* __restrict__ cnt, const float* __restrict__ maskf,
                        float* __restrict__ dinv, int* __restrict__ off,
                        int* __restrict__ bsum, int N) {
  __shared__ int s[256];
  int i = blockIdx.x * 256 + threadIdx.x;
  int v = (i < N) ? cnt[i] : 0;
  if (i < N) {
    float d = (float)v + maskf[i];
    dinv[i] = (d > 0.f) ? rsqrtf(d) : 0.f;
  }
  s[threadIdx.x] = v;
  __syncthreads();
#pragma unroll
  for (int d = 1; d < 256; d <<= 1) {
    int t = (threadIdx.x >= d) ? s[threadIdx.x - d] : 0;
    __syncthreads();
    s[threadIdx.x] += t;
    __syncthreads();
  }
  if (i < N) off[i] = s[threadIdx.x] - v;
  if (threadIdx.x == 255) bsum[blockIdx.x] = s[255];
}

__global__ void k_scan2(int* __restrict__ bsum, int nb) {
  __shared__ int s[256];
  int v = (threadIdx.x < nb) ? bsum[threadIdx.x] : 0;
  s[threadIdx.x] = v;
  __syncthreads();
#pragma unroll
  for (int d = 1; d < 256; d <<= 1) {
    int t = (threadIdx.x >= d) ? s[threadIdx.x - d] : 0;
    __syncthreads();
    s[threadIdx.x] += t;
    __syncthreads();
  }
  if (threadIdx.x < nb) bsum[threadIdx.x] = s[threadIdx.x] - v;
}

// scan3 + cursor + per-graph bounds (batch sorted -> boundary detection, no atomics)
__global__ void k_scan3(int* __restrict__ off, const int* __restrict__ bsum,
                        int* __restrict__ cursor, const int* __restrict__ batch,
                        int* __restrict__ gs, int* __restrict__ ge, int N) {
  int i = blockIdx.x * 256 + threadIdx.x;
  if (i >= N) return;
  int o = off[i] + bsum[blockIdx.x];
  off[i] = o;
  cursor[i] = o;
  int b = batch[i];
  if (i == 0 || batch[i - 1] != b) gs[b] = i;
  if (i == N - 1 || batch[i + 1] != b) ge[b] = i;
}

// Fill CSR: packed (src, w_bits) per kept edge, grouped by dst.
__global__ void k_fill(const int* __restrict__ src, const int* __restrict__ dst,
                       const float* __restrict__ dinv, int* __restrict__ cursor,
                       int2* __restrict__ csr, int E) {
  int e = blockIdx.x * blockDim.x + threadIdx.x;
  if (e >= E) return;
  int s = src[e], d = dst[e];
  float w = dinv[s] * dinv[d];
  if (w > 0.f) {
    int p = atomicAdd(&cursor[d], 1);
    csr[p] = make_int2(s, __float_as_int(w));
  }
}

// P[d][:] = dinv[d]^2 * Hin[d][:] + sum_e w_e * Hin[src_e][:]
// One wave per dst. CSR entries preloaded into lane regs; 8 edges / iteration
// via 8-lane groups (each lane covers 8 cols = 2 float4 loads -> 2x MLP).
__global__ __launch_bounds__(256) void k_agg(const float* __restrict__ Hin,
                                             const float* __restrict__ dinv,
                                             const int* __restrict__ off,
                                             const int* __restrict__ cnt,
                                             const int2* __restrict__ csr,
                                             float* __restrict__ P, int N) {
  const int lane = threadIdx.x & 63;
  const int wid = threadIdx.x >> 6;
  const int d = blockIdx.x * 4 + wid;
  if (d >= N) return;
  const int grp = lane >> 3;   // which edge of the octet
  const int q = lane & 7;      // column group: cols 8q..8q+7
  const int base = off[d];
  const int n = cnt[d];
  float4 a0 = make_float4(0.f, 0.f, 0.f, 0.f);
  float4 a1 = make_float4(0.f, 0.f, 0.f, 0.f);
  int done = 0;
  while (done < n) {
    const int chunk = min(n - done, 64);
    int2 ce = (lane < chunk) ? csr[base + done + lane] : make_int2(0, 0);
    const int rounds = (chunk + 7) & ~7;
#pragma unroll 2
    for (int i = 0; i < rounds; i += 8) {
      const int j = i + grp;
      const int s = __shfl(ce.x, j);
      const float w = __int_as_float(__shfl(ce.y, j));  // 0 for padded lanes
      const float4 v0 = *(const float4*)&Hin[(long)s * 64 + q * 8];
      const float4 v1 = *(const float4*)&Hin[(long)s * 64 + q * 8 + 4];
      a0.x = fmaf(v0.x, w, a0.x);
      a0.y = fmaf(v0.y, w, a0.y);
      a0.z = fmaf(v0.z, w, a0.z);
      a0.w = fmaf(v0.w, w, a0.w);
      a1.x = fmaf(v1.x, w, a1.x);
      a1.y = fmaf(v1.y, w, a1.y);
      a1.z = fmaf(v1.z, w, a1.z);
      a1.w = fmaf(v1.w, w, a1.w);
    }
    done += chunk;
  }
  // reduce the 8 edge-groups (lanes sharing q share columns)
#pragma unroll
  for (int m = 8; m <= 32; m <<= 1) {
    a0.x += __shfl_xor(a0.x, m);
    a0.y += __shfl_xor(a0.y, m);
    a0.z += __shfl_xor(a0.z, m);
    a0.w += __shfl_xor(a0.w, m);
    a1.x += __shfl_xor(a1.x, m);
    a1.y += __shfl_xor(a1.y, m);
    a1.z += __shfl_xor(a1.z, m);
    a1.w += __shfl_xor(a1.w, m);
  }
  if (grp == 0) {
    const float di = dinv[d];
    const float dii = di * di;
    const float4 v0 = *(const float4*)&Hin[(long)d * 64 + q * 8];
    const float4 v1 = *(const float4*)&Hin[(long)d * 64 + q * 8 + 4];
    a0.x = fmaf(v0.x, dii, a0.x);
    a0.y = fmaf(v0.y, dii, a0.y);
    a0.z = fmaf(v0.z, dii, a0.z);
    a0.w = fmaf(v0.w, dii, a0.w);
    a1.x = fmaf(v1.x, dii, a1.x);
    a1.y = fmaf(v1.y, dii, a1.y);
    a1.z = fmaf(v1.z, dii, a1.z);
    a1.w = fmaf(v1.w, dii, a1.w);
    *(float4*)&P[(long)d * 64 + q * 8] = a0;
    *(float4*)&P[(long)d * 64 + q * 8 + 4] = a1;
  }
}

// Hout = relu(A @ W + b); one wave per row, W column per lane.
__global__ __launch_bounds__(256) void k_gemm(const float* __restrict__ A,
                                              const float* __restrict__ W,
                                              const float* __restrict__ b,
                                              float* __restrict__ T, int nrows) {
  const int lane = threadIdx.x & 63;
  const int wid = threadIdx.x >> 6;
  float wcol[64];
#pragma unroll
  for (int k = 0; k < 64; ++k) wcol[k] = W[k * 64 + lane];
  const float bl = b[lane];
  for (int r = blockIdx.x * 4 + wid; r < nrows; r += gridDim.x * 4) {
    const float av = A[(long)r * 64 + lane];
    float acc = bl;
#pragma unroll
    for (int k = 0; k < 64; ++k) acc = fmaf(__shfl(av, k), wcol[k], acc);
    T[(long)r * 64 + lane] = fmaxf(acc, 0.f);
  }
}

// Fused: per-graph max-pool over kept nodes -> MLP head -> out[grp][:]
__global__ __launch_bounds__(256) void k_pool_head(
    const float* __restrict__ H, const float* __restrict__ maskf,
    const int* __restrict__ gs, const int* __restrict__ ge,
    const float* __restrict__ fw1, const float* __restrict__ fb1,
    const float* __restrict__ fw2, const float* __restrict__ fb2,
    float* __restrict__ out, int N, int C) {
  __shared__ float sP[4][64];
  __shared__ float sg[64];
  __shared__ float sg2[64];
  const int grp = blockIdx.x;
  const int lane = threadIdx.x & 63, wid = threadIdx.x >> 6;
  const int s = gs[grp], e = ge[grp];
  float v = 0.f;
  if (s <= e) {
    for (int i = s + wid; i <= e; i += 4)
      if (maskf[i] != 0.f) v = fmaxf(v, H[(long)i * 64 + lane]);
  }
  sP[wid][lane] = v;
  __syncthreads();
  if (wid == 0)
    sg[lane] = fmaxf(fmaxf(sP[0][lane], sP[1][lane]), fmaxf(sP[2][lane], sP[3][lane]));
  __syncthreads();
  if (threadIdx.x < 64) {
    const int f = threadIdx.x;
    float acc = fb1[f];
#pragma unroll 8
    for (int k = 0; k < 64; ++k) acc = fmaf(sg[k], fw1[k * 64 + f], acc);
    sg2[f] = fmaxf(acc, 0.f);
  }
  __syncthreads();
  if (threadIdx.x < C) {
    const int c = threadIdx.x;
    float acc = fb2[c];
#pragma unroll 8
    for (int k = 0; k < 64; ++k) acc = fmaf(sg2[k], fw2[k * C + c], acc);
    out[grp * C + c] = acc;
  }
}

extern "C" void kernel_launch(void* const* d_in, const int* in_sizes, int n_in,
                              void* d_out, int out_size, void* d_ws, size_t ws_size,
                              hipStream_t stream) {
  const float* x    = (const float*)d_in[0];
  const int*   ei   = (const int*)d_in[1];
  const int*   batch= (const int*)d_in[2];
  const void*  mraw = d_in[3];
  const float* W1   = (const float*)d_in[4];
  const float* b1   = (const float*)d_in[5];
  const float* W2   = (const float*)d_in[6];
  const float* b2   = (const float*)d_in[7];
  const float* W3   = (const float*)d_in[8];
  const float* b3   = (const float*)d_in[9];
  const float* fw1  = (const float*)d_in[10];
  const float* fb1  = (const float*)d_in[11];
  const float* fw2  = (const float*)d_in[12];
  const float* fb2  = (const float*)d_in[13];
  float* out = (float*)d_out;

  const int N = in_sizes[0] / 64;
  const int E = in_sizes[1] / 2;
  const int C = in_sizes[13];
  const int* src = ei;
  const int* dst = ei + E;
  const int G = out_size / C;

  char* ws = (char*)d_ws;
  size_t off_b = 0;
  auto alloc = [&](size_t bytes) -> void* {
    void* p = ws + off_b;
    off_b += (bytes + 255) & ~(size_t)255;
    return p;
  };
  int*   flag   = (int*)alloc(sizeof(int));
  float* maskf  = (float*)alloc((size_t)N * 4);
  int*   cnt    = (int*)alloc((size_t)N * 4);
  float* dinv   = (float*)alloc((size_t)N * 4);
  int*   off    = (int*)alloc((size_t)N * 4);
  int*   cursor = (int*)alloc((size_t)N * 4);
  int*   bsum   = (int*)alloc(256 * 4);
  int*   gs     = (int*)alloc((size_t)G * 4);
  int*   ge     = (int*)alloc((size_t)G * 4);
  int2*  csr    = (int2*)alloc((size_t)E * 8);
  float* P      = (float*)alloc((size_t)N * 64 * 4);
  float* HA     = (float*)alloc((size_t)N * 64 * 4);
  float* HB     = (float*)alloc((size_t)N * 64 * 4);
  (void)ws_size;

  hipMemsetAsync(flag, 0, sizeof(int), stream);

  const int nb = (N + 255) / 256;
  k_detect<<<32, 256, 0, stream>>>((const unsigned int*)mraw, N / 4, flag);
  k_maskf<<<nb, 256, 0, stream>>>(mraw, flag, maskf, cnt, gs, ge, N, G);
  k_cnt<<<(E + 255) / 256, 256, 0, stream>>>(src, dst, maskf, cnt, E);
  k_scan1<<<nb, 256, 0, stream>>>(cnt, maskf, dinv, off, bsum, N);
  k_scan2<<<1, 256, 0, stream>>>(bsum, nb);
  k_scan3<<<nb, 256, 0, stream>>>(off, bsum, cursor, batch, gs, ge, N);
  k_fill<<<(E + 255) / 256, 256, 0, stream>>>(src, dst, dinv, cursor, csr, E);

  const int agg_blocks = (N + 3) / 4;
  const int gemm_blocks = 2048;
  // layer 1
  k_agg<<<agg_blocks, 256, 0, stream>>>(x, dinv, off, cnt, csr, P, N);
  k_gemm<<<gemm_blocks, 256, 0, stream>>>(P, W1, b1, HA, N);
  // layer 2
  k_agg<<<agg_blocks, 256, 0, stream>>>(HA, dinv, off, cnt, csr, P, N);
  k_gemm<<<gemm_blocks, 256, 0, stream>>>(P, W2, b2, HB, N);
  // layer 3
  k_agg<<<agg_blocks, 256, 0, stream>>>(HB, dinv, off, cnt, csr, P, N);
  k_gemm<<<gemm_blocks, 256, 0, stream>>>(P, W3, b3, HA, N);

  k_pool_head<<<G, 256, 0, stream>>>(HA, maskf, gs, ge, fw1, fb1, fw2, fb2, out, N, C);
}